// Round 13
// baseline (244.531 us; speedup 1.0000x reference)
//
#include <hip/hip_runtime.h>

#define DIM 256
// contiguous combined layout (query path): per node 3 slots (x, oh, th)
#define NODE_U2 192
#define NODE_U4 96
#define SLOT_OH_U4 32
#define SLOT_TH_U4 64

// dimension slicing (gather path): 8 slices x 32 dims (64 B = 4 uint4)
#define NSL 8
// LDS edge-stage capacity (64 uniform-degree rows; max ~64*45 < 4096)
#define ECAP 4096
#define NBIN 64

// ---- bf16 helpers ---------------------------------------------------------
__device__ __forceinline__ unsigned int f2bf_rne(float f) {
    unsigned int u = __float_as_uint(f);
    return (u + 0x7fffu + ((u >> 16) & 1u)) >> 16;
}
__device__ __forceinline__ float bf_lo(unsigned int u) {
    return __uint_as_float(u << 16);
}
__device__ __forceinline__ float bf_hi(unsigned int u) {
    return __uint_as_float(u & 0xffff0000u);
}
__device__ __forceinline__ unsigned int pack2(float a, float b) {
    return f2bf_rne(a) | (f2bf_rne(b) << 16);
}

#define ACC8(v)                                            \
    do {                                                   \
        a0 += bf_lo((v).x); a1 += bf_hi((v).x);            \
        a2 += bf_lo((v).y); a3 += bf_hi((v).y);            \
        a4 += bf_lo((v).z); a5 += bf_hi((v).z);            \
        a6 += bf_lo((v).w); a7 += bf_hi((v).w);            \
    } while (0)

// ---------------------------------------------------------------------------
// 1) fused: x (contiguous cmb slot + sliced slab) + XCD-partitioned degree
// ---------------------------------------------------------------------------
__global__ void x_and_hist_kernel(const float* __restrict__ nv,
                                  const float* __restrict__ w,
                                  uint2* __restrict__ cmb,
                                  uint2* __restrict__ xs_sl,
                                  int total_u2, int N,
                                  const int* __restrict__ adj_row,
                                  int* __restrict__ deg, int E, int per_part) {
    int i0 = blockIdx.x * blockDim.x + threadIdx.x;
    int stride = gridDim.x * blockDim.x;
    for (int i = i0; i < total_u2; i += stride) {
        float4 v = reinterpret_cast<const float4*>(nv)[i];
        int node = i >> 6;
        int j = i & 63;
        float wt = w[node];
        uint2 r;
        r.x = pack2(v.x * wt, v.y * wt);
        r.y = pack2(v.z * wt, v.w * wt);
        cmb[(size_t)node * NODE_U2 + j] = r;
        int s = j >> 3;
        xs_sl[((size_t)s * N + node) * 8 + (j & 7)] = r;
    }
    int bp = blockIdx.x & 7;
    unsigned lo = (unsigned)(bp * per_part);
    int chunk = blockIdx.x >> 3;
    int nchunks = gridDim.x >> 3;
    int E4 = E >> 2;
    for (int i = chunk * 256 + threadIdx.x; i < E4; i += nchunks * 256) {
        int4 r4 = reinterpret_cast<const int4*>(adj_row)[i];
        if ((unsigned)(r4.x - lo) < (unsigned)per_part) atomicAdd(&deg[r4.x], 1);
        if ((unsigned)(r4.y - lo) < (unsigned)per_part) atomicAdd(&deg[r4.y], 1);
        if ((unsigned)(r4.z - lo) < (unsigned)per_part) atomicAdd(&deg[r4.z], 1);
        if ((unsigned)(r4.w - lo) < (unsigned)per_part) atomicAdd(&deg[r4.w], 1);
    }
    if (bp == 0 && chunk == 0) {
        for (int e = (E & ~3) + threadIdx.x; e < E; e += 256)
            atomicAdd(&deg[adj_row[e]], 1);
    }
}

// ---------------------------------------------------------------------------
// degree binning: per-block 64-bin histogram -> blockBin[bin*nblk + blk]
// ---------------------------------------------------------------------------
__global__ void bin_count_kernel(const int* __restrict__ deg,
                                 int* __restrict__ blockBin, int n, int nblk) {
    __shared__ int h[NBIN];
    if (threadIdx.x < NBIN) h[threadIdx.x] = 0;
    __syncthreads();
    int i = blockIdx.x * 256 + threadIdx.x;
    if (i < n) {
        int b = deg[i]; b = b > NBIN - 1 ? NBIN - 1 : b;
        atomicAdd(&h[b], 1);
    }
    __syncthreads();
    if (threadIdx.x < NBIN)
        blockBin[(size_t)threadIdx.x * nblk + blockIdx.x] = h[threadIdx.x];
}

// deterministic rank assignment (within-block order via LDS atomics is the
// only nondeterminism; it permutes equal-degree rows -> results unaffected)
__global__ void rank_assign_kernel(const int* __restrict__ deg,
                                   const int* __restrict__ off,
                                   int* __restrict__ rank2node,
                                   int* __restrict__ node2rank,
                                   int* __restrict__ degR, int n, int nblk) {
    __shared__ int h[NBIN];
    __shared__ int base[NBIN];
    if (threadIdx.x < NBIN) h[threadIdx.x] = 0;
    __syncthreads();
    int i = blockIdx.x * 256 + threadIdx.x;
    int b = 0, loc = 0, d = 0;
    bool act = i < n;
    if (act) {
        d = deg[i]; b = d > NBIN - 1 ? NBIN - 1 : d;
        loc = atomicAdd(&h[b], 1);
    }
    __syncthreads();
    if (threadIdx.x < NBIN)
        base[threadIdx.x] = off[(size_t)threadIdx.x * nblk + blockIdx.x];
    __syncthreads();
    if (act) {
        int r = base[b] + loc;
        rank2node[r] = i;
        node2rank[i] = r;
        degR[r] = d;
    }
}

// ---------------------------------------------------------------------------
// generic 2-level scan pieces
// ---------------------------------------------------------------------------
__global__ void block_sum_kernel(const int* __restrict__ in,
                                 int* __restrict__ sums, int n) {
    __shared__ int lds[256];
    int i = blockIdx.x * 256 + threadIdx.x;
    lds[threadIdx.x] = (i < n) ? in[i] : 0;
    __syncthreads();
    #pragma unroll
    for (int off = 128; off > 0; off >>= 1) {
        if (threadIdx.x < off) lds[threadIdx.x] += lds[threadIdx.x + off];
        __syncthreads();
    }
    if (threadIdx.x == 0) sums[blockIdx.x] = lds[0];
}

__global__ void scan_sums_kernel(int* __restrict__ sums, int nb,
                                 int* __restrict__ total_out) {
    __shared__ int lds[256];
    int v = (threadIdx.x < nb) ? sums[threadIdx.x] : 0;
    lds[threadIdx.x] = v;
    __syncthreads();
    #pragma unroll
    for (int off = 1; off < 256; off <<= 1) {
        int t = (threadIdx.x >= off) ? lds[threadIdx.x - off] : 0;
        __syncthreads();
        lds[threadIdx.x] += t;
        __syncthreads();
    }
    if (threadIdx.x < nb) sums[threadIdx.x] = lds[threadIdx.x] - v;
    if (threadIdx.x == 255) *total_out = lds[255];
}

__global__ void scan_block_kernel(const int* __restrict__ in,
                                  const int* __restrict__ sums,
                                  int* __restrict__ out1,
                                  int* __restrict__ out2, int n) {
    __shared__ int lds[256];
    int i = blockIdx.x * 256 + threadIdx.x;
    int v = (i < n) ? in[i] : 0;
    lds[threadIdx.x] = v;
    __syncthreads();
    #pragma unroll
    for (int off = 1; off < 256; off <<= 1) {
        int t = (threadIdx.x >= off) ? lds[threadIdx.x - off] : 0;
        __syncthreads();
        lds[threadIdx.x] += t;
        __syncthreads();
    }
    if (i < n) {
        int excl = sums[blockIdx.x] + lds[threadIdx.x] - v;
        out1[i] = excl;
        out2[i] = excl;
    }
}

// ---------------------------------------------------------------------------
// rank-partitioned permutation build (u16 cols); partition p owns rank range
// -> cursor/perm segments stay in one XCD's L2
// ---------------------------------------------------------------------------
__global__ void scatter_perm_part_kernel(const int* __restrict__ row,
                                         const int* __restrict__ col,
                                         const int* __restrict__ node2rank,
                                         int* __restrict__ cursor,
                                         unsigned short* __restrict__ perm,
                                         int E, int per_part) {
    int bp = blockIdx.x & 7;
    unsigned lo = (unsigned)(bp * per_part);
    int chunk = blockIdx.x >> 3;
    int nchunks = gridDim.x >> 3;
    int E4 = E >> 2;
    for (int i = chunk * 256 + threadIdx.x; i < E4; i += nchunks * 256) {
        int4 r4 = reinterpret_cast<const int4*>(row)[i];
        int e = i << 2;
        int k0 = node2rank[r4.x];
        int k1 = node2rank[r4.y];
        int k2 = node2rank[r4.z];
        int k3 = node2rank[r4.w];
        if ((unsigned)(k0 - lo) < (unsigned)per_part) {
            int pos = atomicAdd(&cursor[k0], 1);
            perm[pos] = (unsigned short)col[e];
        }
        if ((unsigned)(k1 - lo) < (unsigned)per_part) {
            int pos = atomicAdd(&cursor[k1], 1);
            perm[pos] = (unsigned short)col[e + 1];
        }
        if ((unsigned)(k2 - lo) < (unsigned)per_part) {
            int pos = atomicAdd(&cursor[k2], 1);
            perm[pos] = (unsigned short)col[e + 2];
        }
        if ((unsigned)(k3 - lo) < (unsigned)per_part) {
            int pos = atomicAdd(&cursor[k3], 1);
            perm[pos] = (unsigned short)col[e + 3];
        }
    }
    if (bp == 0 && chunk == 0) {
        for (int e = (E & ~3) + threadIdx.x; e < E; e += 256) {
            int k = node2rank[row[e]];
            int pos = atomicAdd(&cursor[k], 1);
            perm[pos] = (unsigned short)col[e];
        }
    }
}

// ---------------------------------------------------------------------------
// Dimension-sliced gather over degree-sorted ranks (uniform loop counts).
// slice s = blockIdx % 8 (XCD-pinned); block = 64 consecutive ranks.
// ---------------------------------------------------------------------------
__global__ void gather_sliced_kernel(const int* __restrict__ row_ptr,
                                     const unsigned short* __restrict__ perm,
                                     const int* __restrict__ rank2node,
                                     const uint4* __restrict__ src_sl,
                                     uint4* __restrict__ dst_sl,
                                     uint4* __restrict__ dst_cmb_slot,
                                     int N) {
    __shared__ unsigned short eidx[ECAP];
    int s = blockIdx.x & (NSL - 1);
    int rb = blockIdx.x >> 3;
    int r0 = rb * 64;
    int rlim = r0 + 64 < N ? r0 + 64 : N;
    int beg0 = row_ptr[r0];
    int end0 = row_ptr[rlim];
    int L = end0 - beg0;
    int Lc = L < ECAP ? L : ECAP;
    for (int i = threadIdx.x; i < Lc; i += 256) eidx[i] = perm[beg0 + i];
    __syncthreads();

    int g = threadIdx.x >> 2;
    int j = threadIdx.x & 3;
    int r = r0 + g;
    if (r >= N) return;

    int node = rank2node[r];
    int beg = row_ptr[r];
    int end = row_ptr[r + 1];
    const uint4* base = src_sl + (size_t)s * N * 4;

    float a0 = 0.f, a1 = 0.f, a2 = 0.f, a3 = 0.f;
    float a4 = 0.f, a5 = 0.f, a6 = 0.f, a7 = 0.f;

    if (L <= ECAP) {
        int o = beg - beg0;
        int cnt = end - beg;
        int k = 0;
        for (; k + 3 < cnt; k += 4) {
            int c0 = eidx[o + k];
            int c1 = eidx[o + k + 1];
            int c2 = eidx[o + k + 2];
            int c3 = eidx[o + k + 3];
            uint4 v0 = base[(size_t)c0 * 4 + j];
            uint4 v1 = base[(size_t)c1 * 4 + j];
            uint4 v2 = base[(size_t)c2 * 4 + j];
            uint4 v3 = base[(size_t)c3 * 4 + j];
            ACC8(v0); ACC8(v1); ACC8(v2); ACC8(v3);
        }
        for (; k < cnt; ++k) {
            uint4 v = base[(size_t)eidx[o + k] * 4 + j];
            ACC8(v);
        }
    } else {
        for (int e = beg; e < end; ++e) {
            uint4 v = base[(size_t)perm[e] * 4 + j];
            ACC8(v);
        }
    }

    uint4 o4;
    o4.x = pack2(a0, a1);
    o4.y = pack2(a2, a3);
    o4.z = pack2(a4, a5);
    o4.w = pack2(a6, a7);
    if (dst_sl) dst_sl[((size_t)s * N + node) * 4 + j] = o4;
    dst_cmb_slot[(size_t)node * NODE_U4 + s * 4 + j] = o4;
}

// ---------------------------------------------------------------------------
// Query: 32 lanes per query (uint4 loads), 2 queries per wave (contiguous cmb)
// ---------------------------------------------------------------------------
__global__ void query_kernel(const int* __restrict__ es,
                             const int* __restrict__ et,
                             const uint4* __restrict__ cmb4,
                             const int* __restrict__ deg,
                             float* __restrict__ out, int nq) {
    int gid = blockIdx.x * blockDim.x + threadIdx.x;
    int q = gid >> 5;
    if (q >= nq) return;
    int l = gid & 31;

    int s = es[q];
    int t = et[q];

    const uint4* ns = cmb4 + (size_t)s * NODE_U4;
    const uint4* nt = cmb4 + (size_t)t * NODE_U4;

    uint4 vxs = ns[l];
    uint4 vos = ns[SLOT_OH_U4 + l];
    uint4 vts = ns[SLOT_TH_U4 + l];
    uint4 vxt = nt[l];
    uint4 vot = nt[SLOT_OH_U4 + l];
    uint4 vtt = nt[SLOT_TH_U4 + l];
    float ds = (float)deg[s];
    float dt = (float)deg[t];

    float c11 = 0.f, c12 = 0.f, c22 = 0.f, cs = 0.f;
    const unsigned int* pxs = (const unsigned int*)&vxs;
    const unsigned int* pxt = (const unsigned int*)&vxt;
    const unsigned int* pos_ = (const unsigned int*)&vos;
    const unsigned int* pot = (const unsigned int*)&vot;
    const unsigned int* pts = (const unsigned int*)&vts;
    const unsigned int* ptt = (const unsigned int*)&vtt;
    #pragma unroll
    for (int k = 0; k < 4; ++k) {
        {
            float fxs = bf_lo(pxs[k]), fxt = bf_lo(pxt[k]);
            float fos = bf_lo(pos_[k]), fot = bf_lo(pot[k]);
            float fts = bf_lo(pts[k]), ftt = bf_lo(ptt[k]);
            c11 += fos * fot;
            c12 += fos * ftt + fts * fot;
            float as = fts - ds * fxs;
            float bt = ftt - dt * fxt;
            c22 += as * bt;
            cs  += fos * fts + fot * ftt;
        }
        {
            float fxs = bf_hi(pxs[k]), fxt = bf_hi(pxt[k]);
            float fos = bf_hi(pos_[k]), fot = bf_hi(pot[k]);
            float fts = bf_hi(pts[k]), ftt = bf_hi(ptt[k]);
            c11 += fos * fot;
            c12 += fos * ftt + fts * fot;
            float as = fts - ds * fxs;
            float bt = ftt - dt * fxt;
            c22 += as * bt;
            cs  += fos * fts + fot * ftt;
        }
    }

    #pragma unroll
    for (int off = 16; off > 0; off >>= 1) {
        c11 += __shfl_xor(c11, off);
        c12 += __shfl_xor(c12, off);
        c22 += __shfl_xor(c22, off);
        cs  += __shfl_xor(cs,  off);
    }

    if (l == 0) {
        out[q]          = c11;
        out[nq + q]     = c12;
        out[2 * nq + q] = c22;
        out[3 * nq + q] = cs;
    }
}

// ---------------------------------------------------------------------------
extern "C" void kernel_launch(void* const* d_in, const int* in_sizes, int n_in,
                              void* d_out, int out_size, void* d_ws, size_t ws_size,
                              hipStream_t stream) {
    const int*   edges        = (const int*)  d_in[0];
    const int*   adj_row      = (const int*)  d_in[1];
    const int*   adj_col      = (const int*)  d_in[2];
    const float* node_weight  = (const float*)d_in[3];
    const float* node_vectors = (const float*)d_in[4];

    const int EQ = in_sizes[0] / 2;
    const int E  = in_sizes[1];
    const int N  = in_sizes[3];

    const int nbB = (N + 255) / 256;           // 196 blocks over nodes
    const int n1  = NBIN * nbB;                // bin-major array size (12544)
    const int nbS = (n1 + 255) / 256;          // 49

    // workspace layout
    uint2* cmb   = (uint2*)d_ws;                        // N*192 uint2
    uint2* xs_sl = cmb + (size_t)N * NODE_U2;           // N*64 uint2
    uint2* oh_sl = xs_sl + (size_t)N * 64;              // N*64 uint2
    int* deg      = (int*)(oh_sl + (size_t)N * 64);     // [N]
    int* node2rank = deg + N;                           // [N]
    int* rank2node = node2rank + N;                     // [N]
    int* degR     = rank2node + N;                      // [N]
    int* row_ptr  = degR + N;                           // [N+1] rank space
    int* cursor   = row_ptr + (N + 1);                  // [N]
    int* blockBin = cursor + N;                         // [NBIN*nbB]
    int* s1       = blockBin + n1;                      // [256]
    unsigned short* perm = (unsigned short*)(s1 + 256); // [E]

    const int* es = edges;
    const int* et = edges + EQ;
    float* out = (float*)d_out;

    const int per_part_node = (N + 7) / 8;
    const int per_part_rank = (N + 7) / 8;

    // --- fused x (both layouts) + partitioned degree histogram ---
    hipMemsetAsync(deg, 0, (size_t)N * sizeof(int), stream);
    int total_u2 = N * 64;
    x_and_hist_kernel<<<2048, 256, 0, stream>>>(node_vectors, node_weight,
                                                cmb, xs_sl, total_u2, N,
                                                adj_row, deg, E, per_part_node);

    // --- degree-sorted rank assignment ---
    bin_count_kernel<<<nbB, 256, 0, stream>>>(deg, blockBin, N, nbB);
    block_sum_kernel<<<nbS, 256, 0, stream>>>(blockBin, s1, n1);
    scan_sums_kernel<<<1, 256, 0, stream>>>(s1, nbS, cursor /*dummy*/);
    scan_block_kernel<<<nbS, 256, 0, stream>>>(blockBin, s1, blockBin,
                                               blockBin, n1);
    rank_assign_kernel<<<nbB, 256, 0, stream>>>(deg, blockBin, rank2node,
                                                node2rank, degR, N, nbB);

    // --- rank-space CSR (row_ptr + cursor) ---
    block_sum_kernel<<<nbB, 256, 0, stream>>>(degR, s1, N);
    scan_sums_kernel<<<1, 256, 0, stream>>>(s1, nbB, row_ptr + N);
    scan_block_kernel<<<nbB, 256, 0, stream>>>(degR, s1, row_ptr, cursor, N);
    scatter_perm_part_kernel<<<2048, 256, 0, stream>>>(adj_row, adj_col,
                                                       node2rank, cursor, perm,
                                                       E, per_part_rank);

    // --- one_hop / two_hop via XCD-pinned sliced gather (rank order) ---
    const uint4* xs4 = (const uint4*)xs_sl;
    uint4* oh4 = (uint4*)oh_sl;
    uint4* cmb4 = (uint4*)cmb;
    int nrb = (N + 63) / 64;
    int gblocks = nrb * NSL;
    gather_sliced_kernel<<<gblocks, 256, 0, stream>>>(
        row_ptr, perm, rank2node, xs4, oh4, cmb4 + SLOT_OH_U4, N);
    gather_sliced_kernel<<<gblocks, 256, 0, stream>>>(
        row_ptr, perm, rank2node, (const uint4*)oh4, (uint4*)nullptr,
        cmb4 + SLOT_TH_U4, N);

    // --- queries ---
    int qthreads = EQ * 32;
    query_kernel<<<(qthreads + 255) / 256, 256, 0, stream>>>(
        es, et, cmb4, deg, out, EQ);
}

// Round 14
// 243.676 us; speedup vs baseline: 1.0035x; 1.0035x over previous
//
#include <hip/hip_runtime.h>

#define DIM 256
// contiguous combined layout (query path): per node 3 slots (x, oh, th)
#define NODE_U2 192
#define NODE_U4 96
#define SLOT_OH_U4 32
#define SLOT_TH_U4 64

// dimension slicing (gather path): 8 slices x 32 dims (64 B = 4 uint4)
#define NSL 8
// LDS edge-stage capacity
#define ECAP 2048

// ---- bf16 helpers ---------------------------------------------------------
__device__ __forceinline__ unsigned int f2bf_rne(float f) {
    unsigned int u = __float_as_uint(f);
    return (u + 0x7fffu + ((u >> 16) & 1u)) >> 16;
}
__device__ __forceinline__ float bf_lo(unsigned int u) {
    return __uint_as_float(u << 16);
}
__device__ __forceinline__ float bf_hi(unsigned int u) {
    return __uint_as_float(u & 0xffff0000u);
}
__device__ __forceinline__ unsigned int pack2(float a, float b) {
    return f2bf_rne(a) | (f2bf_rne(b) << 16);
}

#define ACC8(v)                                            \
    do {                                                   \
        a0 += bf_lo((v).x); a1 += bf_hi((v).x);            \
        a2 += bf_lo((v).y); a3 += bf_hi((v).y);            \
        a4 += bf_lo((v).z); a5 += bf_hi((v).z);            \
        a6 += bf_lo((v).w); a7 += bf_hi((v).w);            \
    } while (0)

// ---------------------------------------------------------------------------
// 1) fused: x (contiguous cmb slot + sliced slab) + partitioned adj-degree
//    histogram + partitioned query-source histogram
// ---------------------------------------------------------------------------
__global__ void x_and_hist_kernel(const float* __restrict__ nv,
                                  const float* __restrict__ w,
                                  uint2* __restrict__ cmb,
                                  uint2* __restrict__ xs_sl,
                                  int total_u2, int N,
                                  const int* __restrict__ adj_row,
                                  int* __restrict__ cnt, int E,
                                  const int* __restrict__ es,
                                  int* __restrict__ qcnt, int EQ,
                                  int per_part) {
    int i0 = blockIdx.x * blockDim.x + threadIdx.x;
    int stride = gridDim.x * blockDim.x;
    for (int i = i0; i < total_u2; i += stride) {
        float4 v = reinterpret_cast<const float4*>(nv)[i];
        int node = i >> 6;
        int j = i & 63;
        float wt = w[node];
        uint2 r;
        r.x = pack2(v.x * wt, v.y * wt);
        r.y = pack2(v.z * wt, v.w * wt);
        cmb[(size_t)node * NODE_U2 + j] = r;
        int s = j >> 3;
        xs_sl[((size_t)s * N + node) * 8 + (j & 7)] = r;
    }
    int bp = blockIdx.x & 7;
    unsigned lo = (unsigned)(bp * per_part);
    int chunk = blockIdx.x >> 3;
    int nchunks = gridDim.x >> 3;
    int E4 = E >> 2;
    for (int i = chunk * 256 + threadIdx.x; i < E4; i += nchunks * 256) {
        int4 r4 = reinterpret_cast<const int4*>(adj_row)[i];
        if ((unsigned)(r4.x - lo) < (unsigned)per_part) atomicAdd(&cnt[r4.x], 1);
        if ((unsigned)(r4.y - lo) < (unsigned)per_part) atomicAdd(&cnt[r4.y], 1);
        if ((unsigned)(r4.z - lo) < (unsigned)per_part) atomicAdd(&cnt[r4.z], 1);
        if ((unsigned)(r4.w - lo) < (unsigned)per_part) atomicAdd(&cnt[r4.w], 1);
    }
    int Q4 = EQ >> 2;
    for (int i = chunk * 256 + threadIdx.x; i < Q4; i += nchunks * 256) {
        int4 s4 = reinterpret_cast<const int4*>(es)[i];
        if ((unsigned)(s4.x - lo) < (unsigned)per_part) atomicAdd(&qcnt[s4.x], 1);
        if ((unsigned)(s4.y - lo) < (unsigned)per_part) atomicAdd(&qcnt[s4.y], 1);
        if ((unsigned)(s4.z - lo) < (unsigned)per_part) atomicAdd(&qcnt[s4.z], 1);
        if ((unsigned)(s4.w - lo) < (unsigned)per_part) atomicAdd(&qcnt[s4.w], 1);
    }
    if (bp == 0 && chunk == 0) {
        for (int e = (E & ~3) + threadIdx.x; e < E; e += 256)
            atomicAdd(&cnt[adj_row[e]], 1);
        for (int q = (EQ & ~3) + threadIdx.x; q < EQ; q += 256)
            atomicAdd(&qcnt[es[q]], 1);
    }
}

// ---------------------------------------------------------------------------
// generic 2-level scan pieces
// ---------------------------------------------------------------------------
__global__ void block_sum_kernel(const int* __restrict__ in,
                                 int* __restrict__ sums, int n) {
    __shared__ int lds[256];
    int i = blockIdx.x * 256 + threadIdx.x;
    lds[threadIdx.x] = (i < n) ? in[i] : 0;
    __syncthreads();
    #pragma unroll
    for (int off = 128; off > 0; off >>= 1) {
        if (threadIdx.x < off) lds[threadIdx.x] += lds[threadIdx.x + off];
        __syncthreads();
    }
    if (threadIdx.x == 0) sums[blockIdx.x] = lds[0];
}

__global__ void scan_sums_kernel(int* __restrict__ sums, int nb,
                                 int* __restrict__ total_out) {
    __shared__ int lds[256];
    int v = (threadIdx.x < nb) ? sums[threadIdx.x] : 0;
    lds[threadIdx.x] = v;
    __syncthreads();
    #pragma unroll
    for (int off = 1; off < 256; off <<= 1) {
        int t = (threadIdx.x >= off) ? lds[threadIdx.x - off] : 0;
        __syncthreads();
        lds[threadIdx.x] += t;
        __syncthreads();
    }
    if (threadIdx.x < nb) sums[threadIdx.x] = lds[threadIdx.x] - v;
    if (threadIdx.x == 255) *total_out = lds[255];
}

__global__ void scan_block_kernel(const int* __restrict__ in,
                                  const int* __restrict__ sums,
                                  int* __restrict__ out1,
                                  int* __restrict__ out2, int n) {
    __shared__ int lds[256];
    int i = blockIdx.x * 256 + threadIdx.x;
    int v = (i < n) ? in[i] : 0;
    lds[threadIdx.x] = v;
    __syncthreads();
    #pragma unroll
    for (int off = 1; off < 256; off <<= 1) {
        int t = (threadIdx.x >= off) ? lds[threadIdx.x - off] : 0;
        __syncthreads();
        lds[threadIdx.x] += t;
        __syncthreads();
    }
    if (i < n) {
        int excl = sums[blockIdx.x] + lds[threadIdx.x] - v;
        out1[i] = excl;
        out2[i] = excl;
    }
}

// ---------------------------------------------------------------------------
// XCD-partitioned permutation build; perm stored as u16 (N < 65536)
// ---------------------------------------------------------------------------
__global__ void scatter_perm_part_kernel(const int* __restrict__ row,
                                         const int* __restrict__ col,
                                         int* __restrict__ cursor,
                                         unsigned short* __restrict__ perm,
                                         int E, int per_part) {
    int bp = blockIdx.x & 7;
    unsigned lo = (unsigned)(bp * per_part);
    int chunk = blockIdx.x >> 3;
    int nchunks = gridDim.x >> 3;
    int E4 = E >> 2;
    for (int i = chunk * 256 + threadIdx.x; i < E4; i += nchunks * 256) {
        int4 r4 = reinterpret_cast<const int4*>(row)[i];
        int e = i << 2;
        if ((unsigned)(r4.x - lo) < (unsigned)per_part) {
            int pos = atomicAdd(&cursor[r4.x], 1);
            perm[pos] = (unsigned short)col[e];
        }
        if ((unsigned)(r4.y - lo) < (unsigned)per_part) {
            int pos = atomicAdd(&cursor[r4.y], 1);
            perm[pos] = (unsigned short)col[e + 1];
        }
        if ((unsigned)(r4.z - lo) < (unsigned)per_part) {
            int pos = atomicAdd(&cursor[r4.z], 1);
            perm[pos] = (unsigned short)col[e + 2];
        }
        if ((unsigned)(r4.w - lo) < (unsigned)per_part) {
            int pos = atomicAdd(&cursor[r4.w], 1);
            perm[pos] = (unsigned short)col[e + 3];
        }
    }
    if (bp == 0 && chunk == 0) {
        for (int e = (E & ~3) + threadIdx.x; e < E; e += 256) {
            int pos = atomicAdd(&cursor[row[e]], 1);
            perm[pos] = (unsigned short)col[e];
        }
    }
}

// ---------------------------------------------------------------------------
// XCD-partitioned query counting-sort scatter: sorted-by-s arrays
// ---------------------------------------------------------------------------
__global__ void qscatter_part_kernel(const int* __restrict__ es,
                                     const int* __restrict__ et,
                                     int* __restrict__ qcur,
                                     int* __restrict__ qs,
                                     int* __restrict__ qt,
                                     int* __restrict__ qidx,
                                     int EQ, int per_part) {
    int bp = blockIdx.x & 7;
    unsigned lo = (unsigned)(bp * per_part);
    int chunk = blockIdx.x >> 3;
    int nchunks = gridDim.x >> 3;
    int Q4 = EQ >> 2;
    for (int i = chunk * 256 + threadIdx.x; i < Q4; i += nchunks * 256) {
        int4 s4 = reinterpret_cast<const int4*>(es)[i];
        int4 t4 = reinterpret_cast<const int4*>(et)[i];
        int q = i << 2;
        if ((unsigned)(s4.x - lo) < (unsigned)per_part) {
            int pos = atomicAdd(&qcur[s4.x], 1);
            qs[pos] = s4.x; qt[pos] = t4.x; qidx[pos] = q;
        }
        if ((unsigned)(s4.y - lo) < (unsigned)per_part) {
            int pos = atomicAdd(&qcur[s4.y], 1);
            qs[pos] = s4.y; qt[pos] = t4.y; qidx[pos] = q + 1;
        }
        if ((unsigned)(s4.z - lo) < (unsigned)per_part) {
            int pos = atomicAdd(&qcur[s4.z], 1);
            qs[pos] = s4.z; qt[pos] = t4.z; qidx[pos] = q + 2;
        }
        if ((unsigned)(s4.w - lo) < (unsigned)per_part) {
            int pos = atomicAdd(&qcur[s4.w], 1);
            qs[pos] = s4.w; qt[pos] = t4.w; qidx[pos] = q + 3;
        }
    }
    if (bp == 0 && chunk == 0) {
        for (int q = (EQ & ~3) + threadIdx.x; q < EQ; q += 256) {
            int s = es[q];
            int pos = atomicAdd(&qcur[s], 1);
            qs[pos] = s; qt[pos] = et[q]; qidx[pos] = q;
        }
    }
}

// ---------------------------------------------------------------------------
// Dimension-sliced gather with LDS-staged u16 edge lists (round-12 proven)
// ---------------------------------------------------------------------------
__global__ void gather_sliced_kernel(const int* __restrict__ row_ptr,
                                     const unsigned short* __restrict__ perm,
                                     const uint4* __restrict__ src_sl,
                                     uint4* __restrict__ dst_sl,
                                     uint4* __restrict__ dst_cmb_slot,
                                     int N) {
    __shared__ unsigned short eidx[ECAP];
    int s = blockIdx.x & (NSL - 1);
    int rb = blockIdx.x >> 3;
    int r0 = rb * 64;
    int rlim = r0 + 64 < N ? r0 + 64 : N;
    int beg0 = row_ptr[r0];
    int end0 = row_ptr[rlim];
    int L = end0 - beg0;
    int Lc = L < ECAP ? L : ECAP;
    for (int i = threadIdx.x; i < Lc; i += 256) eidx[i] = perm[beg0 + i];
    __syncthreads();

    int g = threadIdx.x >> 2;
    int j = threadIdx.x & 3;
    int r = r0 + g;
    if (r >= N) return;

    int beg = row_ptr[r];
    int end = row_ptr[r + 1];
    const uint4* base = src_sl + (size_t)s * N * 4;

    float a0 = 0.f, a1 = 0.f, a2 = 0.f, a3 = 0.f;
    float a4 = 0.f, a5 = 0.f, a6 = 0.f, a7 = 0.f;

    if (L <= ECAP) {
        int o = beg - beg0;
        int cnt = end - beg;
        int k = 0;
        for (; k + 3 < cnt; k += 4) {
            int c0 = eidx[o + k];
            int c1 = eidx[o + k + 1];
            int c2 = eidx[o + k + 2];
            int c3 = eidx[o + k + 3];
            uint4 v0 = base[(size_t)c0 * 4 + j];
            uint4 v1 = base[(size_t)c1 * 4 + j];
            uint4 v2 = base[(size_t)c2 * 4 + j];
            uint4 v3 = base[(size_t)c3 * 4 + j];
            ACC8(v0); ACC8(v1); ACC8(v2); ACC8(v3);
        }
        for (; k < cnt; ++k) {
            uint4 v = base[(size_t)eidx[o + k] * 4 + j];
            ACC8(v);
        }
    } else {
        for (int e = beg; e < end; ++e) {
            uint4 v = base[(size_t)perm[e] * 4 + j];
            ACC8(v);
        }
    }

    uint4 o4;
    o4.x = pack2(a0, a1);
    o4.y = pack2(a2, a3);
    o4.z = pack2(a4, a5);
    o4.w = pack2(a6, a7);
    if (dst_sl) dst_sl[((size_t)s * N + r) * 4 + j] = o4;
    dst_cmb_slot[(size_t)r * NODE_U4 + s * 4 + j] = o4;
}

// ---------------------------------------------------------------------------
// Query over sorted-by-s arrays: 32 lanes per query, 2 queries per wave.
// s-side rows stream (sorted); output scattered via qidx.
// ---------------------------------------------------------------------------
__global__ void query_kernel(const int* __restrict__ qs,
                             const int* __restrict__ qt,
                             const int* __restrict__ qidx,
                             const uint4* __restrict__ cmb4,
                             const int* __restrict__ deg,
                             float* __restrict__ out, int nq) {
    int gid = blockIdx.x * blockDim.x + threadIdx.x;
    int q = gid >> 5;
    if (q >= nq) return;
    int l = gid & 31;

    int s = qs[q];
    int t = qt[q];
    int oq = qidx[q];

    const uint4* ns = cmb4 + (size_t)s * NODE_U4;
    const uint4* nt = cmb4 + (size_t)t * NODE_U4;

    uint4 vxs = ns[l];
    uint4 vos = ns[SLOT_OH_U4 + l];
    uint4 vts = ns[SLOT_TH_U4 + l];
    uint4 vxt = nt[l];
    uint4 vot = nt[SLOT_OH_U4 + l];
    uint4 vtt = nt[SLOT_TH_U4 + l];
    float ds = (float)deg[s];
    float dt = (float)deg[t];

    float c11 = 0.f, c12 = 0.f, c22 = 0.f, cs = 0.f;
    const unsigned int* pxs = (const unsigned int*)&vxs;
    const unsigned int* pxt = (const unsigned int*)&vxt;
    const unsigned int* pos_ = (const unsigned int*)&vos;
    const unsigned int* pot = (const unsigned int*)&vot;
    const unsigned int* pts = (const unsigned int*)&vts;
    const unsigned int* ptt = (const unsigned int*)&vtt;
    #pragma unroll
    for (int k = 0; k < 4; ++k) {
        {
            float fxs = bf_lo(pxs[k]), fxt = bf_lo(pxt[k]);
            float fos = bf_lo(pos_[k]), fot = bf_lo(pot[k]);
            float fts = bf_lo(pts[k]), ftt = bf_lo(ptt[k]);
            c11 += fos * fot;
            c12 += fos * ftt + fts * fot;
            float as = fts - ds * fxs;
            float bt = ftt - dt * fxt;
            c22 += as * bt;
            cs  += fos * fts + fot * ftt;
        }
        {
            float fxs = bf_hi(pxs[k]), fxt = bf_hi(pxt[k]);
            float fos = bf_hi(pos_[k]), fot = bf_hi(pot[k]);
            float fts = bf_hi(pts[k]), ftt = bf_hi(ptt[k]);
            c11 += fos * fot;
            c12 += fos * ftt + fts * fot;
            float as = fts - ds * fxs;
            float bt = ftt - dt * fxt;
            c22 += as * bt;
            cs  += fos * fts + fot * ftt;
        }
    }

    #pragma unroll
    for (int off = 16; off > 0; off >>= 1) {
        c11 += __shfl_xor(c11, off);
        c12 += __shfl_xor(c12, off);
        c22 += __shfl_xor(c22, off);
        cs  += __shfl_xor(cs,  off);
    }

    if (l == 0) {
        out[oq]          = c11;
        out[nq + oq]     = c12;
        out[2 * nq + oq] = c22;
        out[3 * nq + oq] = cs;
    }
}

// ---------------------------------------------------------------------------
extern "C" void kernel_launch(void* const* d_in, const int* in_sizes, int n_in,
                              void* d_out, int out_size, void* d_ws, size_t ws_size,
                              hipStream_t stream) {
    const int*   edges        = (const int*)  d_in[0];
    const int*   adj_row      = (const int*)  d_in[1];
    const int*   adj_col      = (const int*)  d_in[2];
    const float* node_weight  = (const float*)d_in[3];
    const float* node_vectors = (const float*)d_in[4];

    const int EQ = in_sizes[0] / 2;
    const int E  = in_sizes[1];
    const int N  = in_sizes[3];

    // workspace layout
    uint2* cmb   = (uint2*)d_ws;                        // N*192 uint2
    uint2* xs_sl = cmb + (size_t)N * NODE_U2;           // N*64 uint2
    uint2* oh_sl = xs_sl + (size_t)N * 64;              // N*64 uint2
    int* row_ptr = (int*)(oh_sl + (size_t)N * 64);      // [N+1]
    int* cursor  = row_ptr + (N + 1);                   // [N]
    int* cnt     = cursor + N;                          // [N]  (also deg)
    int* qcnt    = cnt + N;                             // [N]  (adjacent: one memset)
    int* qcur    = qcnt + N;                            // [N]
    int* qs      = qcur + N;                            // [EQ]
    int* qt      = qs + EQ;                             // [EQ]
    int* qidx    = qt + EQ;                             // [EQ]
    int* s1      = qidx + EQ;                           // [256]
    unsigned short* perm = (unsigned short*)(s1 + 256); // [E]

    const int* es = edges;
    const int* et = edges + EQ;
    float* out = (float*)d_out;

    const int nb0 = (N + 255) / 256;   // 196
    const int per_part = (N + 7) / 8;  // 6250

    // --- fused x (both layouts) + adj histogram + query histogram ---
    hipMemsetAsync(cnt, 0, (size_t)2 * N * sizeof(int), stream);  // cnt+qcnt
    int total_u2 = N * 64;
    x_and_hist_kernel<<<2048, 256, 0, stream>>>(node_vectors, node_weight,
                                                cmb, xs_sl, total_u2, N,
                                                adj_row, cnt, E,
                                                es, qcnt, EQ, per_part);

    // --- CSR scan + partitioned permutation (u16) ---
    block_sum_kernel<<<nb0, 256, 0, stream>>>(cnt, s1, N);
    scan_sums_kernel<<<1, 256, 0, stream>>>(s1, nb0, row_ptr + N);
    scan_block_kernel<<<nb0, 256, 0, stream>>>(cnt, s1, row_ptr, cursor, N);
    scatter_perm_part_kernel<<<2048, 256, 0, stream>>>(adj_row, adj_col,
                                                       cursor, perm, E,
                                                       per_part);

    // --- query counting-sort by source node ---
    block_sum_kernel<<<nb0, 256, 0, stream>>>(qcnt, s1, N);
    scan_sums_kernel<<<1, 256, 0, stream>>>(s1, nb0, s1 + 250);
    scan_block_kernel<<<nb0, 256, 0, stream>>>(qcnt, s1, qcnt, qcur, N);
    qscatter_part_kernel<<<2048, 256, 0, stream>>>(es, et, qcur, qs, qt, qidx,
                                                   EQ, per_part);

    // --- one_hop / two_hop via XCD-pinned sliced gather (LDS u16 stage) ---
    const uint4* xs4 = (const uint4*)xs_sl;
    uint4* oh4 = (uint4*)oh_sl;
    uint4* cmb4 = (uint4*)cmb;
    int nrb = (N + 63) / 64;
    int gblocks = nrb * NSL;
    gather_sliced_kernel<<<gblocks, 256, 0, stream>>>(
        row_ptr, perm, xs4, oh4, cmb4 + SLOT_OH_U4, N);
    gather_sliced_kernel<<<gblocks, 256, 0, stream>>>(
        row_ptr, perm, (const uint4*)oh4, (uint4*)nullptr,
        cmb4 + SLOT_TH_U4, N);

    // --- queries (sorted by s) ---
    int qthreads = EQ * 32;
    query_kernel<<<(qthreads + 255) / 256, 256, 0, stream>>>(
        qs, qt, qidx, cmb4, cnt, out, EQ);
}

// Round 16
// 228.475 us; speedup vs baseline: 1.0703x; 1.0665x over previous
//
#include <hip/hip_runtime.h>

#define DIM 256
// contiguous combined layout (query path): per node 3 slots (x, oh, th)
#define NODE_U2 192
#define NODE_U4 96
#define SLOT_OH_U4 32
#define SLOT_TH_U4 64

// dimension slicing (gather path): 8 slices x 32 dims (64 B = 4 uint4)
#define NSL 8
// LDS edge-stage capacity (u16)
#define ECAP 2048

typedef unsigned int u32x2 __attribute__((ext_vector_type(2)));
typedef unsigned int u32x4 __attribute__((ext_vector_type(4)));

// ---- bf16 helpers ---------------------------------------------------------
__device__ __forceinline__ unsigned int f2bf_rne(float f) {
    unsigned int u = __float_as_uint(f);
    return (u + 0x7fffu + ((u >> 16) & 1u)) >> 16;
}
__device__ __forceinline__ float bf_lo(unsigned int u) {
    return __uint_as_float(u << 16);
}
__device__ __forceinline__ float bf_hi(unsigned int u) {
    return __uint_as_float(u & 0xffff0000u);
}
__device__ __forceinline__ unsigned int pack2(float a, float b) {
    return f2bf_rne(a) | (f2bf_rne(b) << 16);
}

#define ACC8(v)                                            \
    do {                                                   \
        a0 += bf_lo((v).x); a1 += bf_hi((v).x);            \
        a2 += bf_lo((v).y); a3 += bf_hi((v).y);            \
        a4 += bf_lo((v).z); a5 += bf_hi((v).z);            \
        a6 += bf_lo((v).w); a7 += bf_hi((v).w);            \
    } while (0)

// ---------------------------------------------------------------------------
// 1) fused: x (contiguous cmb slot + sliced slab, NT stores) +
//    XCD-partitioned degree histogram
// ---------------------------------------------------------------------------
__global__ void x_and_hist_kernel(const float* __restrict__ nv,
                                  const float* __restrict__ w,
                                  uint2* __restrict__ cmb,
                                  uint2* __restrict__ xs_sl,
                                  int total_u2, int N,
                                  const int* __restrict__ adj_row,
                                  int* __restrict__ cnt, int E, int per_part) {
    int i0 = blockIdx.x * blockDim.x + threadIdx.x;
    int stride = gridDim.x * blockDim.x;
    for (int i = i0; i < total_u2; i += stride) {
        float4 v = reinterpret_cast<const float4*>(nv)[i];
        int node = i >> 6;
        int j = i & 63;
        float wt = w[node];
        u32x2 r;
        r.x = pack2(v.x * wt, v.y * wt);
        r.y = pack2(v.z * wt, v.w * wt);
        __builtin_nontemporal_store(
            r, reinterpret_cast<u32x2*>(&cmb[(size_t)node * NODE_U2 + j]));
        int s = j >> 3;
        __builtin_nontemporal_store(
            r, reinterpret_cast<u32x2*>(
                   &xs_sl[((size_t)s * N + node) * 8 + (j & 7)]));
    }
    int bp = blockIdx.x & 7;
    unsigned lo = (unsigned)(bp * per_part);
    int chunk = blockIdx.x >> 3;
    int nchunks = gridDim.x >> 3;
    int E4 = E >> 2;
    for (int i = chunk * 256 + threadIdx.x; i < E4; i += nchunks * 256) {
        int4 r4 = reinterpret_cast<const int4*>(adj_row)[i];
        if ((unsigned)(r4.x - lo) < (unsigned)per_part) atomicAdd(&cnt[r4.x], 1);
        if ((unsigned)(r4.y - lo) < (unsigned)per_part) atomicAdd(&cnt[r4.y], 1);
        if ((unsigned)(r4.z - lo) < (unsigned)per_part) atomicAdd(&cnt[r4.z], 1);
        if ((unsigned)(r4.w - lo) < (unsigned)per_part) atomicAdd(&cnt[r4.w], 1);
    }
    if (bp == 0 && chunk == 0) {
        for (int e = (E & ~3) + threadIdx.x; e < E; e += 256)
            atomicAdd(&cnt[adj_row[e]], 1);
    }
}

// ---------------------------------------------------------------------------
// generic 2-level scan pieces
// ---------------------------------------------------------------------------
__global__ void block_sum_kernel(const int* __restrict__ in,
                                 int* __restrict__ sums, int n) {
    __shared__ int lds[256];
    int i = blockIdx.x * 256 + threadIdx.x;
    lds[threadIdx.x] = (i < n) ? in[i] : 0;
    __syncthreads();
    #pragma unroll
    for (int off = 128; off > 0; off >>= 1) {
        if (threadIdx.x < off) lds[threadIdx.x] += lds[threadIdx.x + off];
        __syncthreads();
    }
    if (threadIdx.x == 0) sums[blockIdx.x] = lds[0];
}

__global__ void scan_sums_kernel(int* __restrict__ sums, int nb,
                                 int* __restrict__ total_out) {
    __shared__ int lds[256];
    int v = (threadIdx.x < nb) ? sums[threadIdx.x] : 0;
    lds[threadIdx.x] = v;
    __syncthreads();
    #pragma unroll
    for (int off = 1; off < 256; off <<= 1) {
        int t = (threadIdx.x >= off) ? lds[threadIdx.x - off] : 0;
        __syncthreads();
        lds[threadIdx.x] += t;
        __syncthreads();
    }
    if (threadIdx.x < nb) sums[threadIdx.x] = lds[threadIdx.x] - v;
    if (threadIdx.x == 255) *total_out = lds[255];
}

__global__ void scan_block_kernel(const int* __restrict__ in,
                                  const int* __restrict__ sums,
                                  int* __restrict__ out1,
                                  int* __restrict__ out2, int n) {
    __shared__ int lds[256];
    int i = blockIdx.x * 256 + threadIdx.x;
    int v = (i < n) ? in[i] : 0;
    lds[threadIdx.x] = v;
    __syncthreads();
    #pragma unroll
    for (int off = 1; off < 256; off <<= 1) {
        int t = (threadIdx.x >= off) ? lds[threadIdx.x - off] : 0;
        __syncthreads();
        lds[threadIdx.x] += t;
        __syncthreads();
    }
    if (i < n) {
        int excl = sums[blockIdx.x] + lds[threadIdx.x] - v;
        out1[i] = excl;
        out2[i] = excl;
    }
}

// ---------------------------------------------------------------------------
// XCD-partitioned permutation build; perm stored as u16 (N < 65536)
// ---------------------------------------------------------------------------
__global__ void scatter_perm_part_kernel(const int* __restrict__ row,
                                         const int* __restrict__ col,
                                         int* __restrict__ cursor,
                                         unsigned short* __restrict__ perm,
                                         int E, int per_part) {
    int bp = blockIdx.x & 7;
    unsigned lo = (unsigned)(bp * per_part);
    int chunk = blockIdx.x >> 3;
    int nchunks = gridDim.x >> 3;
    int E4 = E >> 2;
    for (int i = chunk * 256 + threadIdx.x; i < E4; i += nchunks * 256) {
        int4 r4 = reinterpret_cast<const int4*>(row)[i];
        int e = i << 2;
        if ((unsigned)(r4.x - lo) < (unsigned)per_part) {
            int pos = atomicAdd(&cursor[r4.x], 1);
            perm[pos] = (unsigned short)col[e];
        }
        if ((unsigned)(r4.y - lo) < (unsigned)per_part) {
            int pos = atomicAdd(&cursor[r4.y], 1);
            perm[pos] = (unsigned short)col[e + 1];
        }
        if ((unsigned)(r4.z - lo) < (unsigned)per_part) {
            int pos = atomicAdd(&cursor[r4.z], 1);
            perm[pos] = (unsigned short)col[e + 2];
        }
        if ((unsigned)(r4.w - lo) < (unsigned)per_part) {
            int pos = atomicAdd(&cursor[r4.w], 1);
            perm[pos] = (unsigned short)col[e + 3];
        }
    }
    if (bp == 0 && chunk == 0) {
        for (int e = (E & ~3) + threadIdx.x; e < E; e += 256) {
            int pos = atomicAdd(&cursor[row[e]], 1);
            perm[pos] = (unsigned short)col[e];
        }
    }
}

// ---------------------------------------------------------------------------
// Dimension-sliced gather with LDS-staged u16 edge lists; NT dst stores so
// the per-XCD 3.2MB src slab stays L2-resident (dst write-allocate was
// evicting it: FETCH 37MB vs ~28MB compulsory).
// ---------------------------------------------------------------------------
__global__ void gather_sliced_kernel(const int* __restrict__ row_ptr,
                                     const unsigned short* __restrict__ perm,
                                     const uint4* __restrict__ src_sl,
                                     uint4* __restrict__ dst_sl,
                                     uint4* __restrict__ dst_cmb_slot,
                                     int N) {
    __shared__ unsigned short eidx[ECAP];
    int s = blockIdx.x & (NSL - 1);
    int rb = blockIdx.x >> 3;
    int r0 = rb * 64;
    int rlim = r0 + 64 < N ? r0 + 64 : N;
    int beg0 = row_ptr[r0];
    int end0 = row_ptr[rlim];
    int L = end0 - beg0;
    int Lc = L < ECAP ? L : ECAP;
    for (int i = threadIdx.x; i < Lc; i += 256) eidx[i] = perm[beg0 + i];
    __syncthreads();

    int g = threadIdx.x >> 2;
    int j = threadIdx.x & 3;
    int r = r0 + g;
    if (r >= N) return;

    int beg = row_ptr[r];
    int end = row_ptr[r + 1];
    const uint4* base = src_sl + (size_t)s * N * 4;

    float a0 = 0.f, a1 = 0.f, a2 = 0.f, a3 = 0.f;
    float a4 = 0.f, a5 = 0.f, a6 = 0.f, a7 = 0.f;

    if (L <= ECAP) {
        int o = beg - beg0;
        int cnt = end - beg;
        int k = 0;
        for (; k + 3 < cnt; k += 4) {
            int c0 = eidx[o + k];
            int c1 = eidx[o + k + 1];
            int c2 = eidx[o + k + 2];
            int c3 = eidx[o + k + 3];
            uint4 v0 = base[(size_t)c0 * 4 + j];
            uint4 v1 = base[(size_t)c1 * 4 + j];
            uint4 v2 = base[(size_t)c2 * 4 + j];
            uint4 v3 = base[(size_t)c3 * 4 + j];
            ACC8(v0); ACC8(v1); ACC8(v2); ACC8(v3);
        }
        for (; k < cnt; ++k) {
            uint4 v = base[(size_t)eidx[o + k] * 4 + j];
            ACC8(v);
        }
    } else {
        for (int e = beg; e < end; ++e) {
            uint4 v = base[(size_t)perm[e] * 4 + j];
            ACC8(v);
        }
    }

    u32x4 o4;
    o4.x = pack2(a0, a1);
    o4.y = pack2(a2, a3);
    o4.z = pack2(a4, a5);
    o4.w = pack2(a6, a7);
    if (dst_sl)
        __builtin_nontemporal_store(
            o4, reinterpret_cast<u32x4*>(&dst_sl[((size_t)s * N + r) * 4 + j]));
    __builtin_nontemporal_store(
        o4, reinterpret_cast<u32x4*>(
                &dst_cmb_slot[(size_t)r * NODE_U4 + s * 4 + j]));
}

// ---------------------------------------------------------------------------
// Query: 32 lanes per query (uint4 loads), 2 queries per wave (contiguous cmb)
// ---------------------------------------------------------------------------
__global__ void query_kernel(const int* __restrict__ es,
                             const int* __restrict__ et,
                             const uint4* __restrict__ cmb4,
                             const int* __restrict__ deg,
                             float* __restrict__ out, int nq) {
    int gid = blockIdx.x * blockDim.x + threadIdx.x;
    int q = gid >> 5;
    if (q >= nq) return;
    int l = gid & 31;

    int s = es[q];
    int t = et[q];

    const uint4* ns = cmb4 + (size_t)s * NODE_U4;
    const uint4* nt = cmb4 + (size_t)t * NODE_U4;

    uint4 vxs = ns[l];
    uint4 vos = ns[SLOT_OH_U4 + l];
    uint4 vts = ns[SLOT_TH_U4 + l];
    uint4 vxt = nt[l];
    uint4 vot = nt[SLOT_OH_U4 + l];
    uint4 vtt = nt[SLOT_TH_U4 + l];
    float ds = (float)deg[s];
    float dt = (float)deg[t];

    float c11 = 0.f, c12 = 0.f, c22 = 0.f, cs = 0.f;
    const unsigned int* pxs = (const unsigned int*)&vxs;
    const unsigned int* pxt = (const unsigned int*)&vxt;
    const unsigned int* pos_ = (const unsigned int*)&vos;
    const unsigned int* pot = (const unsigned int*)&vot;
    const unsigned int* pts = (const unsigned int*)&vts;
    const unsigned int* ptt = (const unsigned int*)&vtt;
    #pragma unroll
    for (int k = 0; k < 4; ++k) {
        {
            float fxs = bf_lo(pxs[k]), fxt = bf_lo(pxt[k]);
            float fos = bf_lo(pos_[k]), fot = bf_lo(pot[k]);
            float fts = bf_lo(pts[k]), ftt = bf_lo(ptt[k]);
            c11 += fos * fot;
            c12 += fos * ftt + fts * fot;
            float as = fts - ds * fxs;
            float bt = ftt - dt * fxt;
            c22 += as * bt;
            cs  += fos * fts + fot * ftt;
        }
        {
            float fxs = bf_hi(pxs[k]), fxt = bf_hi(pxt[k]);
            float fos = bf_hi(pos_[k]), fot = bf_hi(pot[k]);
            float fts = bf_hi(pts[k]), ftt = bf_hi(ptt[k]);
            c11 += fos * fot;
            c12 += fos * ftt + fts * fot;
            float as = fts - ds * fxs;
            float bt = ftt - dt * fxt;
            c22 += as * bt;
            cs  += fos * fts + fot * ftt;
        }
    }

    #pragma unroll
    for (int off = 16; off > 0; off >>= 1) {
        c11 += __shfl_xor(c11, off);
        c12 += __shfl_xor(c12, off);
        c22 += __shfl_xor(c22, off);
        cs  += __shfl_xor(cs,  off);
    }

    if (l == 0) {
        out[q]          = c11;
        out[nq + q]     = c12;
        out[2 * nq + q] = c22;
        out[3 * nq + q] = cs;
    }
}

// ---------------------------------------------------------------------------
extern "C" void kernel_launch(void* const* d_in, const int* in_sizes, int n_in,
                              void* d_out, int out_size, void* d_ws, size_t ws_size,
                              hipStream_t stream) {
    const int*   edges        = (const int*)  d_in[0];
    const int*   adj_row      = (const int*)  d_in[1];
    const int*   adj_col      = (const int*)  d_in[2];
    const float* node_weight  = (const float*)d_in[3];
    const float* node_vectors = (const float*)d_in[4];

    const int EQ = in_sizes[0] / 2;
    const int E  = in_sizes[1];
    const int N  = in_sizes[3];

    // workspace layout
    uint2* cmb   = (uint2*)d_ws;                        // N*192 uint2
    uint2* xs_sl = cmb + (size_t)N * NODE_U2;           // N*64 uint2
    uint2* oh_sl = xs_sl + (size_t)N * 64;              // N*64 uint2
    int* row_ptr = (int*)(oh_sl + (size_t)N * 64);      // [N+1]
    int* cursor  = row_ptr + (N + 1);                   // [N]
    int* cnt     = cursor + N;                          // [N] (deg)
    int* s1      = cnt + N;                             // [256]
    unsigned short* perm = (unsigned short*)(s1 + 256); // [E]

    const int* es = edges;
    const int* et = edges + EQ;
    float* out = (float*)d_out;

    const int nb0 = (N + 255) / 256;   // 196
    const int per_part = (N + 7) / 8;  // 6250

    // --- fused x (both layouts, NT stores) + partitioned histogram ---
    hipMemsetAsync(cnt, 0, (size_t)N * sizeof(int), stream);
    int total_u2 = N * 64;
    x_and_hist_kernel<<<2048, 256, 0, stream>>>(node_vectors, node_weight,
                                                cmb, xs_sl, total_u2, N,
                                                adj_row, cnt, E, per_part);

    // --- CSR scan + partitioned permutation (u16) ---
    block_sum_kernel<<<nb0, 256, 0, stream>>>(cnt, s1, N);
    scan_sums_kernel<<<1, 256, 0, stream>>>(s1, nb0, row_ptr + N);
    scan_block_kernel<<<nb0, 256, 0, stream>>>(cnt, s1, row_ptr, cursor, N);
    scatter_perm_part_kernel<<<2048, 256, 0, stream>>>(adj_row, adj_col,
                                                       cursor, perm, E,
                                                       per_part);

    // --- one_hop / two_hop via XCD-pinned sliced gather (NT dst) ---
    const uint4* xs4 = (const uint4*)xs_sl;
    uint4* oh4 = (uint4*)oh_sl;
    uint4* cmb4 = (uint4*)cmb;
    int nrb = (N + 63) / 64;
    int gblocks = nrb * NSL;
    gather_sliced_kernel<<<gblocks, 256, 0, stream>>>(
        row_ptr, perm, xs4, oh4, cmb4 + SLOT_OH_U4, N);
    gather_sliced_kernel<<<gblocks, 256, 0, stream>>>(
        row_ptr, perm, (const uint4*)oh4, (uint4*)nullptr,
        cmb4 + SLOT_TH_U4, N);

    // --- queries (unsorted, contiguous cmb) ---
    int qthreads = EQ * 32;
    query_kernel<<<(qthreads + 255) / 256, 256, 0, stream>>>(
        es, et, cmb4, cnt, out, EQ);
}